// Round 3
// baseline (184.119 us; speedup 1.0000x reference)
//
#include <hip/hip_runtime.h>
#include <hip/hip_bf16.h>

// Greedy CTC decode:
//   index[t] = argmax_v emission[t, v]   (first occurrence on ties)
//   keep[t]  = (index[t] != 0) && (t == 0 || index[t] != index[t-1])
// (char mapping in the reference is injective in index, so comparing raw
//  indices is equivalent to comparing chars.)
//
// Layout of d_out (int32): [0, T)  = index, [T, 2T) = keep (0/1).

#define T_ROWS 65536
#define V_LABELS 512

__global__ __launch_bounds__(256) void ctc_argmax_kernel(
    const float* __restrict__ em, int* __restrict__ out_idx) {
    // one 64-lane wave per row
    const int wave = (blockIdx.x * blockDim.x + threadIdx.x) >> 6;
    const int lane = threadIdx.x & 63;
    if (wave >= T_ROWS) return;

    const float4* row = reinterpret_cast<const float4*>(
        em + (size_t)wave * V_LABELS);

    // lane i reads float4 #i (elems 4i..4i+3) and float4 #(i+64)
    // (elems 256+4i..256+4i+3) — each load instruction fully coalesced.
    float4 a = row[lane];
    float4 b = row[lane + 64];

    float bv = a.x;
    int bi = 4 * lane;
    // ascending index order + strict '>' keeps the FIRST max per lane
    if (a.y > bv) { bv = a.y; bi = 4 * lane + 1; }
    if (a.z > bv) { bv = a.z; bi = 4 * lane + 2; }
    if (a.w > bv) { bv = a.w; bi = 4 * lane + 3; }
    if (b.x > bv) { bv = b.x; bi = 256 + 4 * lane; }
    if (b.y > bv) { bv = b.y; bi = 256 + 4 * lane + 1; }
    if (b.z > bv) { bv = b.z; bi = 256 + 4 * lane + 2; }
    if (b.w > bv) { bv = b.w; bi = 256 + 4 * lane + 3; }

    // 64-lane butterfly reduce; tie-break: smaller index wins
    #pragma unroll
    for (int m = 1; m < 64; m <<= 1) {
        float ov = __shfl_xor(bv, m, 64);
        int   oi = __shfl_xor(bi, m, 64);
        if (ov > bv || (ov == bv && oi < bi)) { bv = ov; bi = oi; }
    }

    if (lane == 0) out_idx[wave] = bi;
}

__global__ __launch_bounds__(256) void ctc_keep_kernel(
    const int* __restrict__ idx, int* __restrict__ keep) {
    const int t = blockIdx.x * blockDim.x + threadIdx.x;
    if (t >= T_ROWS) return;
    const int cur = idx[t];
    bool k;
    if (t == 0) {
        k = (cur != 0);                      // prev sentinel -2 never matches
    } else {
        const int prev = idx[t - 1];
        k = (cur != 0) && (cur != prev);
    }
    keep[t] = k ? 1 : 0;
}

extern "C" void kernel_launch(void* const* d_in, const int* in_sizes, int n_in,
                              void* d_out, int out_size, void* d_ws, size_t ws_size,
                              hipStream_t stream) {
    const float* em = (const float*)d_in[0];
    int* out = (int*)d_out;
    int* out_idx  = out;           // [0, T)
    int* out_keep = out + T_ROWS;  // [T, 2T)

    // argmax: one wave per row, 4 waves per 256-thread block
    const int waves_per_block = 256 / 64;
    const int grid_argmax = T_ROWS / waves_per_block;  // 16384
    ctc_argmax_kernel<<<grid_argmax, 256, 0, stream>>>(em, out_idx);

    // keep mask: trivial elementwise pass over the index array
    const int grid_keep = (T_ROWS + 255) / 256;        // 256
    ctc_keep_kernel<<<grid_keep, 256, 0, stream>>>(out_idx, out_keep);
}